// Round 12
// baseline (130.158 us; speedup 1.0000x reference)
//
#include <hip/hip_runtime.h>
#include <stdint.h>

// Problem constants (match reference)
#define BB 16384
#define SS 20
#define DD 128
#define EPSV 1e-5f

// R12: break the 4-waves/SIMD residency granule. One wave = 1 batch row;
// lane owns d0 = 2*lane, d0+1. Main-loop state BY CONSTRUCTION <= ~60 VGPR:
//   xq0[10]+xq1[10] packed f16 s-pairs (20), 8 bperm results, 6 accumulators,
//   ~20 ITER temps. Tokens live in SGPRs (wave-uniform b via readfirstlane ->
//   s_load, R7-proven). Two-pass prologue (R11-proven): pass A streams emb for
//   f32 stats storing nothing; pass B re-reads (L1-hot 6 KB) and packs f16.
// __launch_bounds__(256, 8) caps VGPR at 64 -> 8 waves/SIMD. This is NOT the
// R6 mistake (cap 64 vs ~150 needed -> spill); here need ~58. Tripwire:
// FETCH_SIZE >> 1.5 MB means spill -> revert.
// Gate = fdot2 on packed regs, 4 split accumulator chains (ILP). Conv taps
// extracted from packed halves (R10-verified tap map, absmax 3.9e-3).

typedef __fp16 half2_t __attribute__((ext_vector_type(2)));

#define BPERMU(addr, v) ((uint32_t)__builtin_amdgcn_ds_bpermute((addr), (int)(v)))

static __device__ __forceinline__ float lo16(uint32_t u) {
    return (float)__builtin_bit_cast(half2_t, u)[0];
}
static __device__ __forceinline__ float hi16(uint32_t u) {
    return (float)__builtin_bit_cast(half2_t, u)[1];
}
static __device__ __forceinline__ uint32_t pk16(float a, float b) {
    return __builtin_bit_cast(uint32_t, __builtin_amdgcn_cvt_pkrtz(a, b));
}
static __device__ __forceinline__ float fdot2f(uint32_t a, uint32_t b, float c) {
    return __builtin_amdgcn_fdot2(__builtin_bit_cast(half2_t, a),
                                  __builtin_bit_cast(half2_t, b), c, false);
}

// ---- prep: pack gate_w [20][20] f32 -> [20][10] f16x2 in ws ----
__global__ void pack_gate_kernel(const float* __restrict__ gate_w,
                                 uint32_t*    __restrict__ ws) {
    const int i = threadIdx.x;            // single block of 256
    if (i < SS * (SS / 2)) {
        const int t = i / (SS / 2), p = i % (SS / 2);
        ws[i] = pk16(gate_w[t * SS + 2 * p], gate_w[t * SS + 2 * p + 1]);
    }
}

// One t-iteration; EX = lo16/hi16 selects s within the pair p = t>>1.
// Taps (R10-verified): A=lane-2, B=lane-1, C=lane+1, D=lane+2 packed regs.
#define ITER(t, EX)                                                          \
  {                                                                          \
    /* gate row t: 20 fdot2 in 4 split chains (ILP), f32 accumulate */       \
    float g0a = gate_b[t], g1a = g0a, g0b = 0.f, g1b = 0.f;                  \
    _Pragma("unroll")                                                        \
    for (int q = 0; q < 5; ++q) {                                            \
      const uint32_t hw = gw_pk[(t) * (SS/2) + q];                           \
      g0a = fdot2f(xq0[q], hw, g0a);                                         \
      g1a = fdot2f(xq1[q], hw, g1a);                                         \
    }                                                                        \
    _Pragma("unroll")                                                        \
    for (int q = 5; q < 10; ++q) {                                           \
      const uint32_t hw = gw_pk[(t) * (SS/2) + q];                           \
      g0b = fdot2f(xq0[q], hw, g0b);                                         \
      g1b = fdot2f(xq1[q], hw, g1b);                                         \
    }                                                                        \
    const float g0 = g0a + g0b, g1 = g1a + g1b;                              \
    /* conv taps from packed halves */                                       \
    const float Ae0 = EX(A0), Ae1 = EX(A1);                                  \
    const float Be0 = EX(B0), Be1 = EX(B1);                                  \
    const float Ce0 = EX(C0), Ce1 = EX(C1);                                  \
    const float De0 = EX(D0), De1 = EX(D1);                                  \
    const float Oe0 = EX(xq0[(t) >> 1]), Oe1 = EX(xq1[(t) >> 1]);            \
    const float wa0 = w0[(t)*3+0], wa2 = w0[(t)*3+2];   /* dil 1 */          \
    const float wb0 = w1[(t)*3+0], wb2 = w1[(t)*3+2];   /* dil 2 */          \
    const float wc0 = w2[(t)*3+0], wc2 = w2[(t)*3+2];   /* dil 4 */          \
    const float cw   = w0[(t)*3+1] + w1[(t)*3+1] + w2[(t)*3+1];              \
    const float bias = b0[t] + b1[t] + b2[t];                                \
    float xd0 = bias;                                                        \
    xd0 = fmaf(wc0, Ae0, xd0);   /* d-4 */                                   \
    xd0 = fmaf(wb0, Be0, xd0);   /* d-2 */                                   \
    xd0 = fmaf(wa0, Be1, xd0);   /* d-1 */                                   \
    xd0 = fmaf(cw,  Oe0, xd0);   /* d   */                                   \
    xd0 = fmaf(wa2, Oe1, xd0);   /* d+1 */                                   \
    xd0 = fmaf(wb2, Ce0, xd0);   /* d+2 */                                   \
    xd0 = fmaf(wc2, De0, xd0);   /* d+4 */                                   \
    float xd1 = bias;                                                        \
    xd1 = fmaf(wc0, Ae1, xd1);   /* d-4 */                                   \
    xd1 = fmaf(wb0, Be1, xd1);   /* d-2 */                                   \
    xd1 = fmaf(wa0, Oe0, xd1);   /* d-1 */                                   \
    xd1 = fmaf(cw,  Oe1, xd1);   /* d   */                                   \
    xd1 = fmaf(wa2, Ce0, xd1);   /* d+1 */                                   \
    xd1 = fmaf(wb2, Ce1, xd1);   /* d+2 */                                   \
    xd1 = fmaf(wc2, De1, xd1);   /* d+4 */                                   \
    const float pl = post_w[t] * logit_w[t];                                 \
    const float h0 = xd0 * (g0 * __builtin_amdgcn_rcpf(1.f + __expf(-g0)));  \
    const float h1 = xd1 * (g1 * __builtin_amdgcn_rcpf(1.f + __expf(-g1)));  \
    m20 = fmaf(h0, h0, m20);                                                 \
    m21 = fmaf(h1, h1, m21);                                                 \
    ac0 = fmaf(h0, pl, ac0);                                                 \
    ac1 = fmaf(h1, pl, ac1);                                                 \
  }

__global__ __launch_bounds__(256, 8) void fused_mdt_kernel(
    const int*      __restrict__ tokens,   // [B,S]
    const float*    __restrict__ emb,      // [V,D] (6 KB, cache-resident)
    const float*    __restrict__ pre_w,    // [S]
    const float*    __restrict__ w0, const float* __restrict__ b0,
    const float*    __restrict__ w1, const float* __restrict__ b1,
    const float*    __restrict__ w2, const float* __restrict__ b2,
    const uint32_t* __restrict__ gw_pk,    // [S][S/2] f16x2 (from prep)
    const float*    __restrict__ gate_b,   // [S]
    const float*    __restrict__ post_w,   // [S]
    const float*    __restrict__ logit_w,  // [1,S,1] -> flat [S]
    float*          __restrict__ out)      // [B,1,D] -> flat [B*D]
{
    const int tid  = threadIdx.x;
    const int lane = tid & 63;             // one row per wave
    const int b    = __builtin_amdgcn_readfirstlane(blockIdx.x * 4 + (tid >> 6));
    const int d0   = lane << 1;

    // edge masks ('same' zero padding) + bpermute addresses
    const bool eL1 = (lane == 0);
    const bool eL2 = (lane <  2);
    const bool eR1 = (lane == 63);
    const bool eR2 = (lane >= 62);
    const int aL1 = (lane - 1) << 2;
    const int aL2 = (lane - 2) << 2;
    const int aR1 = (lane + 1) << 2;
    const int aR2 = (lane + 2) << 2;

    const int* tb = tokens + b * SS;       // wave-uniform -> SGPR s_loads

    // ---- pass A: stream emb for RMS stats + residual dot; store nothing ----
    float ms0 = 0.f, ms1 = 0.f, a10 = 0.f, a11 = 0.f;
    #pragma unroll
    for (int s = 0; s < SS; ++s) {
        const float2 v = *reinterpret_cast<const float2*>(emb + tb[s] * DD + d0);
        ms0 = fmaf(v.x, v.x, ms0);
        ms1 = fmaf(v.y, v.y, ms1);
        const float lw = logit_w[s];
        a10 = fmaf(v.x, lw, a10);
        a11 = fmaf(v.y, lw, a11);
    }
    const float r0 = rsqrtf(ms0 * (1.f/SS) + EPSV);
    const float r1 = rsqrtf(ms1 * (1.f/SS) + EPSV);

    // fence: pass-B loads must not hoist above pass A (would fatten live set)
    __builtin_amdgcn_sched_barrier(0);

    // ---- pass B: re-read emb (L1-hot), normalize, pack f16 s-pairs ----
    uint32_t xq0[SS/2], xq1[SS/2];
    #pragma unroll
    for (int p = 0; p < SS/2; ++p) {
        const float2 va = *reinterpret_cast<const float2*>(emb + tb[2*p]   * DD + d0);
        const float2 vb = *reinterpret_cast<const float2*>(emb + tb[2*p+1] * DD + d0);
        const float wA = pre_w[2*p], wB = pre_w[2*p+1];
        xq0[p] = pk16(va.x * (r0 * wA), vb.x * (r0 * wB));
        xq1[p] = pk16(va.y * (r1 * wA), vb.y * (r1 * wB));
    }

    __builtin_amdgcn_sched_barrier(0);

    // ---- main loop: 8 bpermutes per s-pair serve rows 2p and 2p+1 ----
    float m20 = 0.f, m21 = 0.f, ac0 = 0.f, ac1 = 0.f;
    #pragma unroll
    for (int p = 0; p < SS/2; ++p) {
        uint32_t A0 = BPERMU(aL2, xq0[p]), A1 = BPERMU(aL2, xq1[p]);  // lane-2
        uint32_t B0 = BPERMU(aL1, xq0[p]), B1 = BPERMU(aL1, xq1[p]);  // lane-1
        uint32_t C0 = BPERMU(aR1, xq0[p]), C1 = BPERMU(aR1, xq1[p]);  // lane+1
        uint32_t D0 = BPERMU(aR2, xq0[p]), D1 = BPERMU(aR2, xq1[p]);  // lane+2
        A0 = eL2 ? 0u : A0;  A1 = eL2 ? 0u : A1;
        B0 = eL1 ? 0u : B0;  B1 = eL1 ? 0u : B1;
        C0 = eR1 ? 0u : C0;  C1 = eR1 ? 0u : C1;
        D0 = eR2 ? 0u : D0;  D1 = eR2 ? 0u : D1;

        ITER(2*p,     lo16)
        ITER(2*p + 1, hi16)
    }

    const float q0 = rsqrtf(m20 * (1.f/SS) + EPSV);
    const float q1 = rsqrtf(m21 * (1.f/SS) + EPSV);

    float2 res;
    res.x = a10 + q0 * ac0;
    res.y = a11 + q1 * ac1;
    *reinterpret_cast<float2*>(out + b * DD + d0) = res;
}

extern "C" void kernel_launch(void* const* d_in, const int* in_sizes, int n_in,
                              void* d_out, int out_size, void* d_ws, size_t ws_size,
                              hipStream_t stream) {
    const int*   tokens  = (const int*)  d_in[0];
    // d_in[1] = number_log — unused by the reference
    const float* emb     = (const float*)d_in[2];
    const float* pre_w   = (const float*)d_in[3];
    const float* w0      = (const float*)d_in[4];
    const float* b0      = (const float*)d_in[5];
    const float* w1      = (const float*)d_in[6];
    const float* b1      = (const float*)d_in[7];
    const float* w2      = (const float*)d_in[8];
    const float* b2      = (const float*)d_in[9];
    const float* gate_w  = (const float*)d_in[10];
    const float* gate_b  = (const float*)d_in[11];
    const float* post_w  = (const float*)d_in[12];
    const float* logit_w = (const float*)d_in[13];
    float*       out     = (float*)d_out;
    uint32_t*    ws      = (uint32_t*)d_ws;

    hipLaunchKernelGGL(pack_gate_kernel, dim3(1), dim3(256), 0, stream,
                       gate_w, ws);

    dim3 grid(BB / 4);   // 4 rows (4 waves) per 256-thread block -> 4096 blocks
    dim3 block(256);
    hipLaunchKernelGGL(fused_mdt_kernel, grid, block, 0, stream,
                       tokens, emb, pre_w, w0, b0, w1, b1, w2, b2,
                       (const uint32_t*)ws, gate_b, post_w, logit_w, out);
}

// Round 13
// 83.841 us; speedup vs baseline: 1.5524x; 1.5524x over previous
//
#include <hip/hip_runtime.h>
#include <stdint.h>

// Problem constants (match reference)
#define BB 16384
#define SS 20
#define DD 128
#define EPSV 1e-5f

// R13 = R12's slim structure with the empirically-correct VGPR cap.
// Evidence: launch_bounds 2nd arg => VGPR cap ~= 256/arg on this compiler
// (R6: (256,4)->64; R12: (256,8)->32+spill). So (256,4) gives the 64-reg
// allocation that the m69 granule table says unlocks 8 waves/SIMD.
// One wave = 1 batch row; lane owns d0=2*lane, d0+1. Persistent state:
// xq0[10]+xq1[10] packed f16 s-pairs (20 VGPR), 6 accumulators. Tokens in
// SGPRs (wave-uniform b -> s_load). Two-pass prologue (R11): pass A streams
// emb for f32 stats storing nothing; pass B re-reads L1-hot emb and packs.
// bpermute: ONE base address (lane-2)<<2; +0/+4/+12/+16 fold into DS offset
// immediates (saves 3 VGPR). Spill tripwire: FETCH_SIZE >> 1.5 MB.

typedef __fp16 half2_t __attribute__((ext_vector_type(2)));

#define BPERMU(addr, v) ((uint32_t)__builtin_amdgcn_ds_bpermute((addr), (int)(v)))

static __device__ __forceinline__ float lo16(uint32_t u) {
    return (float)__builtin_bit_cast(half2_t, u)[0];
}
static __device__ __forceinline__ float hi16(uint32_t u) {
    return (float)__builtin_bit_cast(half2_t, u)[1];
}
static __device__ __forceinline__ uint32_t pk16(float a, float b) {
    return __builtin_bit_cast(uint32_t, __builtin_amdgcn_cvt_pkrtz(a, b));
}
static __device__ __forceinline__ float fdot2f(uint32_t a, uint32_t b, float c) {
    return __builtin_amdgcn_fdot2(__builtin_bit_cast(half2_t, a),
                                  __builtin_bit_cast(half2_t, b), c, false);
}

// ---- prep: pack gate_w [20][20] f32 -> [20][10] f16x2 in ws ----
__global__ void pack_gate_kernel(const float* __restrict__ gate_w,
                                 uint32_t*    __restrict__ ws) {
    const int i = threadIdx.x;            // single block of 256
    if (i < SS * (SS / 2)) {
        const int t = i / (SS / 2), p = i % (SS / 2);
        ws[i] = pk16(gate_w[t * SS + 2 * p], gate_w[t * SS + 2 * p + 1]);
    }
}

// One t-iteration; EX = lo16/hi16 selects s within the pair p = t>>1.
// A=lane-2, B=lane-1, C=lane+1, D=lane+2 packed regs (R10-verified tap map).
#define ITER(t, EX)                                                          \
  {                                                                          \
    /* gate row t: 20 fdot2, 4 split chains (ILP), f32 accumulate */         \
    float g0a = gate_b[t], g1a = g0a, g0b = 0.f, g1b = 0.f;                  \
    _Pragma("unroll")                                                        \
    for (int q = 0; q < 5; ++q) {                                            \
      const uint32_t hw = gw_pk[(t) * (SS/2) + q];                           \
      g0a = fdot2f(xq0[q], hw, g0a);                                         \
      g1a = fdot2f(xq1[q], hw, g1a);                                         \
    }                                                                        \
    _Pragma("unroll")                                                        \
    for (int q = 5; q < 10; ++q) {                                           \
      const uint32_t hw = gw_pk[(t) * (SS/2) + q];                           \
      g0b = fdot2f(xq0[q], hw, g0b);                                         \
      g1b = fdot2f(xq1[q], hw, g1b);                                         \
    }                                                                        \
    const float g0 = g0a + g0b, g1 = g1a + g1b;                              \
    /* conv taps from packed halves */                                       \
    const float Ae0 = EX(A0), Ae1 = EX(A1);                                  \
    const float Be0 = EX(B0), Be1 = EX(B1);                                  \
    const float Ce0 = EX(C0), Ce1 = EX(C1);                                  \
    const float De0 = EX(D0), De1 = EX(D1);                                  \
    const float Oe0 = EX(xq0[(t) >> 1]), Oe1 = EX(xq1[(t) >> 1]);            \
    const float wa0 = w0[(t)*3+0], wa2 = w0[(t)*3+2];   /* dil 1 */          \
    const float wb0 = w1[(t)*3+0], wb2 = w1[(t)*3+2];   /* dil 2 */          \
    const float wc0 = w2[(t)*3+0], wc2 = w2[(t)*3+2];   /* dil 4 */          \
    const float cw   = w0[(t)*3+1] + w1[(t)*3+1] + w2[(t)*3+1];              \
    const float bias = b0[t] + b1[t] + b2[t];                                \
    float xd0 = bias;                                                        \
    xd0 = fmaf(wc0, Ae0, xd0);   /* d-4 */                                   \
    xd0 = fmaf(wb0, Be0, xd0);   /* d-2 */                                   \
    xd0 = fmaf(wa0, Be1, xd0);   /* d-1 */                                   \
    xd0 = fmaf(cw,  Oe0, xd0);   /* d   */                                   \
    xd0 = fmaf(wa2, Oe1, xd0);   /* d+1 */                                   \
    xd0 = fmaf(wb2, Ce0, xd0);   /* d+2 */                                   \
    xd0 = fmaf(wc2, De0, xd0);   /* d+4 */                                   \
    float xd1 = bias;                                                        \
    xd1 = fmaf(wc0, Ae1, xd1);   /* d-4 */                                   \
    xd1 = fmaf(wb0, Be1, xd1);   /* d-2 */                                   \
    xd1 = fmaf(wa0, Oe0, xd1);   /* d-1 */                                   \
    xd1 = fmaf(cw,  Oe1, xd1);   /* d   */                                   \
    xd1 = fmaf(wa2, Ce0, xd1);   /* d+1 */                                   \
    xd1 = fmaf(wb2, Ce1, xd1);   /* d+2 */                                   \
    xd1 = fmaf(wc2, De1, xd1);   /* d+4 */                                   \
    const float pl = post_w[t] * logit_w[t];                                 \
    const float h0 = xd0 * (g0 * __builtin_amdgcn_rcpf(1.f + __expf(-g0)));  \
    const float h1 = xd1 * (g1 * __builtin_amdgcn_rcpf(1.f + __expf(-g1)));  \
    m20 = fmaf(h0, h0, m20);                                                 \
    m21 = fmaf(h1, h1, m21);                                                 \
    ac0 = fmaf(h0, pl, ac0);                                                 \
    ac1 = fmaf(h1, pl, ac1);                                                 \
  }

__global__ __launch_bounds__(256, 4) void fused_mdt_kernel(
    const int*      __restrict__ tokens,   // [B,S]
    const float*    __restrict__ emb,      // [V,D] (6 KB, cache-resident)
    const float*    __restrict__ pre_w,    // [S]
    const float*    __restrict__ w0, const float* __restrict__ b0,
    const float*    __restrict__ w1, const float* __restrict__ b1,
    const float*    __restrict__ w2, const float* __restrict__ b2,
    const uint32_t* __restrict__ gw_pk,    // [S][S/2] f16x2 (from prep)
    const float*    __restrict__ gate_b,   // [S]
    const float*    __restrict__ post_w,   // [S]
    const float*    __restrict__ logit_w,  // [1,S,1] -> flat [S]
    float*          __restrict__ out)      // [B,1,D] -> flat [B*D]
{
    const int tid  = threadIdx.x;
    const int lane = tid & 63;             // one row per wave
    const int b    = __builtin_amdgcn_readfirstlane(blockIdx.x * 4 + (tid >> 6));
    const int d0   = lane << 1;

    // edge masks (kept in scalar condition regs, no VGPR cost)
    const bool eL1 = (lane == 0);
    const bool eL2 = (lane <  2);
    const bool eR1 = (lane == 63);
    const bool eR2 = (lane >= 62);
    // ONE bpermute base; +0/+4/+12/+16 fold into DS offset immediates
    const int ab = (lane - 2) << 2;

    const int* tb = tokens + b * SS;       // wave-uniform -> SGPR s_loads

    // ---- pass A: stream emb for RMS stats + residual dot; store nothing ----
    float ms0 = 0.f, ms1 = 0.f, a10 = 0.f, a11 = 0.f;
    #pragma unroll
    for (int s = 0; s < SS; ++s) {
        const float2 v = *reinterpret_cast<const float2*>(emb + tb[s] * DD + d0);
        ms0 = fmaf(v.x, v.x, ms0);
        ms1 = fmaf(v.y, v.y, ms1);
        const float lw = logit_w[s];
        a10 = fmaf(v.x, lw, a10);
        a11 = fmaf(v.y, lw, a11);
    }
    const float r0 = rsqrtf(ms0 * (1.f/SS) + EPSV);
    const float r1 = rsqrtf(ms1 * (1.f/SS) + EPSV);

    // fence: pass-B loads must not hoist above pass A (would fatten live set)
    __builtin_amdgcn_sched_barrier(0);

    // ---- pass B: re-read emb (L1-hot), normalize, pack f16 s-pairs ----
    uint32_t xq0[SS/2], xq1[SS/2];
    #pragma unroll
    for (int p = 0; p < SS/2; ++p) {
        const float2 va = *reinterpret_cast<const float2*>(emb + tb[2*p]   * DD + d0);
        const float2 vb = *reinterpret_cast<const float2*>(emb + tb[2*p+1] * DD + d0);
        const float wA = pre_w[2*p], wB = pre_w[2*p+1];
        xq0[p] = pk16(va.x * (r0 * wA), vb.x * (r0 * wB));
        xq1[p] = pk16(va.y * (r1 * wA), vb.y * (r1 * wB));
    }

    __builtin_amdgcn_sched_barrier(0);

    // ---- main loop: 8 bpermutes per s-pair serve rows 2p and 2p+1 ----
    float m20 = 0.f, m21 = 0.f, ac0 = 0.f, ac1 = 0.f;
    #pragma unroll
    for (int p = 0; p < SS/2; ++p) {
        uint32_t A0 = BPERMU(ab,      xq0[p]), A1 = BPERMU(ab,      xq1[p]); // lane-2
        uint32_t B0 = BPERMU(ab + 4,  xq0[p]), B1 = BPERMU(ab + 4,  xq1[p]); // lane-1
        uint32_t C0 = BPERMU(ab + 12, xq0[p]), C1 = BPERMU(ab + 12, xq1[p]); // lane+1
        uint32_t D0 = BPERMU(ab + 16, xq0[p]), D1 = BPERMU(ab + 16, xq1[p]); // lane+2
        A0 = eL2 ? 0u : A0;  A1 = eL2 ? 0u : A1;
        B0 = eL1 ? 0u : B0;  B1 = eL1 ? 0u : B1;
        C0 = eR1 ? 0u : C0;  C1 = eR1 ? 0u : C1;
        D0 = eR2 ? 0u : D0;  D1 = eR2 ? 0u : D1;

        ITER(2*p,     lo16)
        ITER(2*p + 1, hi16)
    }

    const float q0 = rsqrtf(m20 * (1.f/SS) + EPSV);
    const float q1 = rsqrtf(m21 * (1.f/SS) + EPSV);

    float2 res;
    res.x = a10 + q0 * ac0;
    res.y = a11 + q1 * ac1;
    *reinterpret_cast<float2*>(out + b * DD + d0) = res;
}

extern "C" void kernel_launch(void* const* d_in, const int* in_sizes, int n_in,
                              void* d_out, int out_size, void* d_ws, size_t ws_size,
                              hipStream_t stream) {
    const int*   tokens  = (const int*)  d_in[0];
    // d_in[1] = number_log — unused by the reference
    const float* emb     = (const float*)d_in[2];
    const float* pre_w   = (const float*)d_in[3];
    const float* w0      = (const float*)d_in[4];
    const float* b0      = (const float*)d_in[5];
    const float* w1      = (const float*)d_in[6];
    const float* b1      = (const float*)d_in[7];
    const float* w2      = (const float*)d_in[8];
    const float* b2      = (const float*)d_in[9];
    const float* gate_w  = (const float*)d_in[10];
    const float* gate_b  = (const float*)d_in[11];
    const float* post_w  = (const float*)d_in[12];
    const float* logit_w = (const float*)d_in[13];
    float*       out     = (float*)d_out;
    uint32_t*    ws      = (uint32_t*)d_ws;

    hipLaunchKernelGGL(pack_gate_kernel, dim3(1), dim3(256), 0, stream,
                       gate_w, ws);

    dim3 grid(BB / 4);   // 4 rows (4 waves) per 256-thread block -> 4096 blocks
    dim3 block(256);
    hipLaunchKernelGGL(fused_mdt_kernel, grid, block, 0, stream,
                       tokens, emb, pre_w, w0, b0, w1, b1, w2, b2,
                       (const uint32_t*)ws, gate_b, post_w, logit_w, out);
}

// Round 14
// 52.310 us; speedup vs baseline: 2.4882x; 1.6028x over previous
//
#include <hip/hip_runtime.h>
#include <stdint.h>

// Problem constants (match reference)
#define BB 16384
#define SS 20
#define DD 128
#define EPSV 1e-5f

// R14: d-PACKED lanes. One wave = 1 batch row; lane owns the d-pair
// (d0=2*lane, d0+1) packed as ONE f16x2 reg per s -> X[20] = 20 VGPR total
// persistent state. Why: R13 proved forcing 64 VGPR via launch_bounds
// doubles the emitted stream (dur 57->84); this structure fits ~55 VGPR
// NATURALLY (no cap) by eliminating the 12 extracts/t (taps stay packed):
//   conv = 7 v_pk_fma_f16 + 2 alignbit per t (tap-pair == neighbor packed reg)
//   gate = 20 v_pk_fma_f16 per t on broadcast-packed weights (s_load)
//   DS   = 4 ds_bpermute per t (lane+-1, +-2), 80/wave (R9 level)
// gate_b added in f32 after accumulation; stats/residual/SiLU/post-RMS f32.
// Two-pass prologue (R11): pass A streams emb for stats, pass B re-reads
// (L1-hot 6 KB) and packs. sched_barrier stops cross-pass hoisting.
// NO launch_bounds min-waves arg (R6/R12/R13 lessons).

typedef __fp16 half2_t __attribute__((ext_vector_type(2)));

#define BPERMU(addr, v) ((uint32_t)__builtin_amdgcn_ds_bpermute((addr), (int)(v)))

static __device__ __forceinline__ uint32_t pk16(float a, float b) {
    return __builtin_bit_cast(uint32_t, __builtin_amdgcn_cvt_pkrtz(a, b));
}
static __device__ __forceinline__ half2_t h2(uint32_t u) {
    return __builtin_bit_cast(half2_t, u);
}

// ---- prep: broadcast-pack gate_w (400) + conv weights (20x8) into ws ----
// ws[0..399]          : gwb[t*20+s] = (w[t][s], w[t][s]) f16x2
// ws[400 + t*8 + 0..7]: {wc0, wb0, wa0, cw, wa2, wb2, wc2, bias} pairs
__global__ void pack_w_kernel(const float* __restrict__ gate_w,
                              const float* __restrict__ w0, const float* __restrict__ b0,
                              const float* __restrict__ w1, const float* __restrict__ b1,
                              const float* __restrict__ w2, const float* __restrict__ b2,
                              uint32_t*    __restrict__ ws) {
    const int i = threadIdx.x;             // single block of 512
    if (i < SS * SS) {
        const float v = gate_w[i];
        ws[i] = pk16(v, v);
    }
    if (i < SS) {
        const float wa0 = w0[i*3+0], wam = w0[i*3+1], wa2 = w0[i*3+2];
        const float wb0 = w1[i*3+0], wbm = w1[i*3+1], wb2 = w1[i*3+2];
        const float wc0 = w2[i*3+0], wcm = w2[i*3+1], wc2 = w2[i*3+2];
        const float cw   = wam + wbm + wcm;
        const float bias = b0[i] + b1[i] + b2[i];
        uint32_t* o = ws + SS * SS + i * 8;
        o[0] = pk16(wc0, wc0);  o[1] = pk16(wb0, wb0);
        o[2] = pk16(wa0, wa0);  o[3] = pk16(cw,  cw);
        o[4] = pk16(wa2, wa2);  o[5] = pk16(wb2, wb2);
        o[6] = pk16(wc2, wc2);  o[7] = pk16(bias, bias);
    }
}

__global__ __launch_bounds__(256) void fused_mdt_kernel(
    const int*      __restrict__ tokens,   // [B,S]
    const float*    __restrict__ emb,      // [V,D] (6 KB, cache-resident)
    const float*    __restrict__ pre_w,    // [S]
    const uint32_t* __restrict__ wpk,      // packed weights (from prep)
    const float*    __restrict__ gate_b,   // [S]
    const float*    __restrict__ post_w,   // [S]
    const float*    __restrict__ logit_w,  // [1,S,1] -> flat [S]
    float*          __restrict__ out)      // [B,1,D] -> flat [B*D]
{
    const int tid  = threadIdx.x;
    const int lane = tid & 63;             // one row per wave
    const int b    = __builtin_amdgcn_readfirstlane(blockIdx.x * 4 + (tid >> 6));
    const int d0   = lane << 1;

    // edge masks (whole packed tap reg zeroed; per-element map verified):
    //   L1 (lane-1): mL1 = lane==0   L2 (lane-2): mL2 = lane<2
    //   R1 (lane+1): mR1 = lane==63  R2 (lane+2): mR2 = lane>=62
    const bool mL1 = (lane == 0);
    const bool mL2 = (lane <  2);
    const bool mR1 = (lane == 63);
    const bool mR2 = (lane >= 62);
    const int aL2 = (lane - 2) << 2;
    const int aL1 = (lane - 1) << 2;
    const int aR1 = (lane + 1) << 2;
    const int aR2 = (lane + 2) << 2;

    const int* tb = tokens + b * SS;       // wave-uniform -> SGPR s_loads

    // ---- pass A: stream emb for RMS stats + residual dot; store nothing ----
    float ms0 = 0.f, ms1 = 0.f, a10 = 0.f, a11 = 0.f;
    #pragma unroll
    for (int s = 0; s < SS; ++s) {
        const float2 v = *reinterpret_cast<const float2*>(emb + tb[s] * DD + d0);
        ms0 = fmaf(v.x, v.x, ms0);
        ms1 = fmaf(v.y, v.y, ms1);
        const float lw = logit_w[s];
        a10 = fmaf(v.x, lw, a10);
        a11 = fmaf(v.y, lw, a11);
    }
    const float r0 = rsqrtf(ms0 * (1.f/SS) + EPSV);
    const float r1 = rsqrtf(ms1 * (1.f/SS) + EPSV);

    __builtin_amdgcn_sched_barrier(0);

    // ---- pass B: re-read emb (L1-hot), normalize, pack d-pairs ----
    uint32_t X[SS];
    #pragma unroll
    for (int s = 0; s < SS; ++s) {
        const float2 v = *reinterpret_cast<const float2*>(emb + tb[s] * DD + d0);
        const float pw = pre_w[s];
        X[s] = pk16(v.x * (r0 * pw), v.y * (r1 * pw));
    }

    __builtin_amdgcn_sched_barrier(0);

    // ---- main loop over t: 4 bperm + packed conv + packed gate + SiLU ----
    float m20 = 0.f, m21 = 0.f, ac0 = 0.f, ac1 = 0.f;
    #pragma unroll
    for (int t = 0; t < SS; ++t) {
        uint32_t L2u = BPERMU(aL2, X[t]);
        uint32_t L1u = BPERMU(aL1, X[t]);
        uint32_t R1u = BPERMU(aR1, X[t]);
        uint32_t R2u = BPERMU(aR2, X[t]);
        L2u = mL2 ? 0u : L2u;
        L1u = mL1 ? 0u : L1u;
        R1u = mR1 ? 0u : R1u;
        R2u = mR2 ? 0u : R2u;
        // lane-pair splices for the +-1 taps:
        //   Dm1 = (lo = L1.hi [d0-1], hi = own.lo [d1-1=d0])
        //   Dp1 = (lo = own.hi [d0+1=d1], hi = R1.lo [d1+1])
        const uint32_t Dm1 = __builtin_amdgcn_alignbit(X[t], L1u, 16);
        const uint32_t Dp1 = __builtin_amdgcn_alignbit(R1u, X[t], 16);

        // conv: 7 packed fma (weights broadcast-packed, s_load uniform)
        const uint32_t* cw8 = wpk + SS * SS + t * 8;
        half2_t xd = h2(cw8[7]);                 // bias pair
        xd += h2(cw8[0]) * h2(L2u);              // d-4
        xd += h2(cw8[1]) * h2(L1u);              // d-2
        xd += h2(cw8[2]) * h2(Dm1);              // d-1
        xd += h2(cw8[3]) * h2(X[t]);             // center (merged)
        xd += h2(cw8[4]) * h2(Dp1);              // d+1
        xd += h2(cw8[5]) * h2(R1u);              // d+2
        xd += h2(cw8[6]) * h2(R2u);              // d+4

        // gate row t: 20 packed fma, 2 split chains; bias added in f32
        half2_t ga = h2(0u), gb = h2(0u);
        #pragma unroll
        for (int q = 0; q < SS / 2; ++q) {
            ga += h2(wpk[t * SS + 2*q    ]) * h2(X[2*q    ]);
            gb += h2(wpk[t * SS + 2*q + 1]) * h2(X[2*q + 1]);
        }
        const half2_t gp = ga + gb;
        const float gbv = gate_b[t];
        const float g0 = (float)gp[0] + gbv;
        const float g1 = (float)gp[1] + gbv;
        const float xd0 = (float)xd[0];
        const float xd1 = (float)xd[1];

        // SiLU + post-RMS accumulation (f32)
        const float pl = post_w[t] * logit_w[t];
        const float h0 = xd0 * (g0 * __builtin_amdgcn_rcpf(1.f + __expf(-g0)));
        const float h1 = xd1 * (g1 * __builtin_amdgcn_rcpf(1.f + __expf(-g1)));
        m20 = fmaf(h0, h0, m20);
        m21 = fmaf(h1, h1, m21);
        ac0 = fmaf(h0, pl, ac0);
        ac1 = fmaf(h1, pl, ac1);
    }

    const float q0 = rsqrtf(m20 * (1.f/SS) + EPSV);
    const float q1 = rsqrtf(m21 * (1.f/SS) + EPSV);

    float2 res;
    res.x = a10 + q0 * ac0;
    res.y = a11 + q1 * ac1;
    *reinterpret_cast<float2*>(out + b * DD + d0) = res;
}

extern "C" void kernel_launch(void* const* d_in, const int* in_sizes, int n_in,
                              void* d_out, int out_size, void* d_ws, size_t ws_size,
                              hipStream_t stream) {
    const int*   tokens  = (const int*)  d_in[0];
    // d_in[1] = number_log — unused by the reference
    const float* emb     = (const float*)d_in[2];
    const float* pre_w   = (const float*)d_in[3];
    const float* w0      = (const float*)d_in[4];
    const float* b0      = (const float*)d_in[5];
    const float* w1      = (const float*)d_in[6];
    const float* b1      = (const float*)d_in[7];
    const float* w2      = (const float*)d_in[8];
    const float* b2      = (const float*)d_in[9];
    const float* gate_w  = (const float*)d_in[10];
    const float* gate_b  = (const float*)d_in[11];
    const float* post_w  = (const float*)d_in[12];
    const float* logit_w = (const float*)d_in[13];
    float*       out     = (float*)d_out;
    uint32_t*    ws      = (uint32_t*)d_ws;

    hipLaunchKernelGGL(pack_w_kernel, dim3(1), dim3(512), 0, stream,
                       gate_w, w0, b0, w1, b1, w2, b2, ws);

    dim3 grid(BB / 4);   // 4 rows (4 waves) per 256-thread block -> 4096 blocks
    dim3 block(256);
    hipLaunchKernelGGL(fused_mdt_kernel, grid, block, 0, stream,
                       tokens, emb, pre_w, (const uint32_t*)ws,
                       gate_b, post_w, logit_w, out);
}

// Round 15
// 52.089 us; speedup vs baseline: 2.4988x; 1.0042x over previous
//
#include <hip/hip_runtime.h>
#include <stdint.h>

// Problem constants (match reference)
#define BB 16384
#define SS 20
#define DD 128
#define EPSV 1e-5f

// R15 = R14's d-packed structure, 2 rows/wave to amortize wave-uniform costs.
// One wave = 2 batch rows (half-wave each); 32 lanes/row; lane owns 4
// consecutive d (d0=4*il) as TWO packed f16x2 regs per s: X0[s]=(d0,d0+1),
// X1[s]=(d0+2,d0+3) -> 40 VGPR persistent. Wave-uniform weight s_loads now
// serve 2 rows (scalar stream/row halves); conv halo needs only lanes +-1 ->
// 4 bperms/t for 4 d (DS/row halves vs R14). 3 alignbit splices make the
// +-1 tap pairs. Gate = 40 pk_fma/t on broadcast-packed weights (per-d cost
// unchanged). Two-pass prologue (R11); tokens reloaded in pass B in int4
// groups so transients die immediately. NO launch-bounds cap (R6/R12/R13).
// Spill tripwire: FETCH_SIZE >> 1.7 MB.

typedef __fp16 half2_t __attribute__((ext_vector_type(2)));

#define BPERMU(addr, v) ((uint32_t)__builtin_amdgcn_ds_bpermute((addr), (int)(v)))

static __device__ __forceinline__ uint32_t pk16(float a, float b) {
    return __builtin_bit_cast(uint32_t, __builtin_amdgcn_cvt_pkrtz(a, b));
}
static __device__ __forceinline__ half2_t h2(uint32_t u) {
    return __builtin_bit_cast(half2_t, u);
}

// ---- prep: broadcast-pack gate_w (400) + conv weights (20x8) into ws ----
// ws[0..399]          : gwb[t*20+s] = (w[t][s], w[t][s]) f16x2
// ws[400 + t*8 + 0..7]: {wc0, wb0, wa0, cw, wa2, wb2, wc2, bias} pairs
__global__ void pack_w_kernel(const float* __restrict__ gate_w,
                              const float* __restrict__ w0, const float* __restrict__ b0,
                              const float* __restrict__ w1, const float* __restrict__ b1,
                              const float* __restrict__ w2, const float* __restrict__ b2,
                              uint32_t*    __restrict__ ws) {
    const int i = threadIdx.x;             // single block of 512
    if (i < SS * SS) {
        const float v = gate_w[i];
        ws[i] = pk16(v, v);
    }
    if (i < SS) {
        const float wa0 = w0[i*3+0], wam = w0[i*3+1], wa2 = w0[i*3+2];
        const float wb0 = w1[i*3+0], wbm = w1[i*3+1], wb2 = w1[i*3+2];
        const float wc0 = w2[i*3+0], wcm = w2[i*3+1], wc2 = w2[i*3+2];
        const float cw   = wam + wbm + wcm;
        const float bias = b0[i] + b1[i] + b2[i];
        uint32_t* o = ws + SS * SS + i * 8;
        o[0] = pk16(wc0, wc0);  o[1] = pk16(wb0, wb0);
        o[2] = pk16(wa0, wa0);  o[3] = pk16(cw,  cw);
        o[4] = pk16(wa2, wa2);  o[5] = pk16(wb2, wb2);
        o[6] = pk16(wc2, wc2);  o[7] = pk16(bias, bias);
    }
}

__global__ __launch_bounds__(256) void fused_mdt_kernel(
    const int*      __restrict__ tokens,   // [B,S]
    const float*    __restrict__ emb,      // [V,D] (6 KB, cache-resident)
    const float*    __restrict__ pre_w,    // [S]
    const uint32_t* __restrict__ wpk,      // packed weights (from prep)
    const float*    __restrict__ gate_b,   // [S]
    const float*    __restrict__ post_w,   // [S]
    const float*    __restrict__ logit_w,  // [1,S,1] -> flat [S]
    float*          __restrict__ out)      // [B,1,D] -> flat [B*D]
{
    const int tid  = threadIdx.x;
    const int lane = tid & 63;             // lane within wave
    const int il   = lane & 31;            // lane within row
    const int b    = blockIdx.x * 8 + (tid >> 5);   // row per half-wave
    const int d0   = il << 2;

    // edge masks: il==0 zeroes LX0,LX1 (all left taps); il==31 zeroes RX0,RX1.
    // Half-wave boundary (lane 32's left neighbor = lane 31, other row) is
    // exactly the il==0 masked case, so no cross-row contamination.
    const bool mL = (il == 0);
    const bool mR = (il == 31);
    const int  la = (lane - 1) << 2;
    const int  ra = (lane + 1) << 2;

    const int4* t4 = reinterpret_cast<const int4*>(tokens + b * SS);

    // ---- pass A: stream emb for RMS stats + residual dot; store nothing ----
    float ms0=0.f, ms1=0.f, ms2=0.f, ms3=0.f;
    float a10=0.f, a11=0.f, a12=0.f, a13=0.f;
    #pragma unroll
    for (int i = 0; i < 5; ++i) {
        const int4 tv = t4[i];
        const int tg[4] = {tv.x, tv.y, tv.z, tv.w};
        #pragma unroll
        for (int j = 0; j < 4; ++j) {
            const int s = 4*i + j;
            const float4 v = *reinterpret_cast<const float4*>(emb + tg[j] * DD + d0);
            ms0 = fmaf(v.x, v.x, ms0); ms1 = fmaf(v.y, v.y, ms1);
            ms2 = fmaf(v.z, v.z, ms2); ms3 = fmaf(v.w, v.w, ms3);
            const float lw = logit_w[s];
            a10 = fmaf(v.x, lw, a10); a11 = fmaf(v.y, lw, a11);
            a12 = fmaf(v.z, lw, a12); a13 = fmaf(v.w, lw, a13);
        }
    }
    const float r0 = rsqrtf(ms0 * (1.f/SS) + EPSV);
    const float r1 = rsqrtf(ms1 * (1.f/SS) + EPSV);
    const float r2 = rsqrtf(ms2 * (1.f/SS) + EPSV);
    const float r3 = rsqrtf(ms3 * (1.f/SS) + EPSV);

    __builtin_amdgcn_sched_barrier(0);

    // ---- pass B: re-read emb (L1-hot) in int4 token groups, pack d-pairs ----
    uint32_t X0[SS], X1[SS];
    #pragma unroll
    for (int i = 0; i < 5; ++i) {
        const int4 tv = t4[i];
        const int tg[4] = {tv.x, tv.y, tv.z, tv.w};
        #pragma unroll
        for (int j = 0; j < 4; ++j) {
            const int s = 4*i + j;
            const float4 v = *reinterpret_cast<const float4*>(emb + tg[j] * DD + d0);
            const float pw = pre_w[s];
            X0[s] = pk16(v.x * (r0 * pw), v.y * (r1 * pw));
            X1[s] = pk16(v.z * (r2 * pw), v.w * (r3 * pw));
        }
    }

    __builtin_amdgcn_sched_barrier(0);

    // ---- main loop over t: 4 bperm + 3 splice + packed conv/gate + SiLU ----
    float m20=0.f, m21=0.f, m22=0.f, m23=0.f;
    float ac0=0.f, ac1=0.f, ac2=0.f, ac3=0.f;
    #pragma unroll
    for (int t = 0; t < SS; ++t) {
        uint32_t LX0 = BPERMU(la, X0[t]);   // (d0-4, d0-3)
        uint32_t LX1 = BPERMU(la, X1[t]);   // (d0-2, d0-1)
        uint32_t RX0 = BPERMU(ra, X0[t]);   // (d0+4, d0+5)
        uint32_t RX1 = BPERMU(ra, X1[t]);   // (d0+6, d0+7)
        LX0 = mL ? 0u : LX0;  LX1 = mL ? 0u : LX1;
        RX0 = mR ? 0u : RX0;  RX1 = mR ? 0u : RX1;
        // +-1 tap pairs (alignbit(A,B,16): lo = B.hi, hi = A.lo):
        const uint32_t Dm1 = __builtin_amdgcn_alignbit(X0[t], LX1, 16);  // (d0-1, d0)
        const uint32_t Dc  = __builtin_amdgcn_alignbit(X1[t], X0[t], 16);// (d0+1, d0+2)
        const uint32_t Dp1 = __builtin_amdgcn_alignbit(RX0, X1[t], 16);  // (d0+3, d0+4)

        // conv: 14 packed fma, weights broadcast-packed (wave-uniform s_load)
        const uint32_t* cw8 = wpk + SS * SS + t * 8;
        half2_t xdA = h2(cw8[7]);                // chunk0 = (d0, d0+1)
        xdA += h2(cw8[0]) * h2(LX0);             // d-4
        xdA += h2(cw8[1]) * h2(LX1);             // d-2
        xdA += h2(cw8[2]) * h2(Dm1);             // d-1
        xdA += h2(cw8[3]) * h2(X0[t]);           // center (merged)
        xdA += h2(cw8[4]) * h2(Dc);              // d+1
        xdA += h2(cw8[5]) * h2(X1[t]);           // d+2
        xdA += h2(cw8[6]) * h2(RX0);             // d+4
        half2_t xdB = h2(cw8[7]);                // chunk1 = (d0+2, d0+3)
        xdB += h2(cw8[0]) * h2(LX1);             // d-4
        xdB += h2(cw8[1]) * h2(X0[t]);           // d-2
        xdB += h2(cw8[2]) * h2(Dc);              // d-1
        xdB += h2(cw8[3]) * h2(X1[t]);           // center
        xdB += h2(cw8[4]) * h2(Dp1);             // d+1
        xdB += h2(cw8[5]) * h2(RX0);             // d+2
        xdB += h2(cw8[6]) * h2(RX1);             // d+4

        // gate row t: 40 packed fma in 4 split chains; bias added in f32
        half2_t gaA = h2(0u), gbA = h2(0u), gaB = h2(0u), gbB = h2(0u);
        #pragma unroll
        for (int q = 0; q < SS / 2; ++q) {
            const half2_t hw0 = h2(wpk[t * SS + 2*q    ]);
            const half2_t hw1 = h2(wpk[t * SS + 2*q + 1]);
            gaA += hw0 * h2(X0[2*q    ]);
            gbA += hw1 * h2(X0[2*q + 1]);
            gaB += hw0 * h2(X1[2*q    ]);
            gbB += hw1 * h2(X1[2*q + 1]);
        }
        const half2_t gpA = gaA + gbA;
        const half2_t gpB = gaB + gbB;
        const float gbv = gate_b[t];
        const float g0 = (float)gpA[0] + gbv;
        const float g1 = (float)gpA[1] + gbv;
        const float g2 = (float)gpB[0] + gbv;
        const float g3 = (float)gpB[1] + gbv;
        const float xd0 = (float)xdA[0], xd1 = (float)xdA[1];
        const float xd2 = (float)xdB[0], xd3 = (float)xdB[1];

        // SiLU + post-RMS accumulation (f32)
        const float pl = post_w[t] * logit_w[t];
        const float h0 = xd0 * (g0 * __builtin_amdgcn_rcpf(1.f + __expf(-g0)));
        const float h1 = xd1 * (g1 * __builtin_amdgcn_rcpf(1.f + __expf(-g1)));
        const float h2v = xd2 * (g2 * __builtin_amdgcn_rcpf(1.f + __expf(-g2)));
        const float h3 = xd3 * (g3 * __builtin_amdgcn_rcpf(1.f + __expf(-g3)));
        m20 = fmaf(h0, h0, m20); m21 = fmaf(h1, h1, m21);
        m22 = fmaf(h2v, h2v, m22); m23 = fmaf(h3, h3, m23);
        ac0 = fmaf(h0, pl, ac0); ac1 = fmaf(h1, pl, ac1);
        ac2 = fmaf(h2v, pl, ac2); ac3 = fmaf(h3, pl, ac3);
    }

    const float q0 = rsqrtf(m20 * (1.f/SS) + EPSV);
    const float q1 = rsqrtf(m21 * (1.f/SS) + EPSV);
    const float q2 = rsqrtf(m22 * (1.f/SS) + EPSV);
    const float q3 = rsqrtf(m23 * (1.f/SS) + EPSV);

    float4 res;
    res.x = a10 + q0 * ac0;
    res.y = a11 + q1 * ac1;
    res.z = a12 + q2 * ac2;
    res.w = a13 + q3 * ac3;
    *reinterpret_cast<float4*>(out + b * DD + d0) = res;
}

extern "C" void kernel_launch(void* const* d_in, const int* in_sizes, int n_in,
                              void* d_out, int out_size, void* d_ws, size_t ws_size,
                              hipStream_t stream) {
    const int*   tokens  = (const int*)  d_in[0];
    // d_in[1] = number_log — unused by the reference
    const float* emb     = (const float*)d_in[2];
    const float* pre_w   = (const float*)d_in[3];
    const float* w0      = (const float*)d_in[4];
    const float* b0      = (const float*)d_in[5];
    const float* w1      = (const float*)d_in[6];
    const float* b1      = (const float*)d_in[7];
    const float* w2      = (const float*)d_in[8];
    const float* b2      = (const float*)d_in[9];
    const float* gate_w  = (const float*)d_in[10];
    const float* gate_b  = (const float*)d_in[11];
    const float* post_w  = (const float*)d_in[12];
    const float* logit_w = (const float*)d_in[13];
    float*       out     = (float*)d_out;
    uint32_t*    ws      = (uint32_t*)d_ws;

    hipLaunchKernelGGL(pack_w_kernel, dim3(1), dim3(512), 0, stream,
                       gate_w, w0, b0, w1, b1, w2, b2, ws);

    dim3 grid(BB / 8);   // 8 rows (4 waves x 2) per 256-thread block
    dim3 block(256);
    hipLaunchKernelGGL(fused_mdt_kernel, grid, block, 0, stream,
                       tokens, emb, pre_w, (const uint32_t*)ws,
                       gate_b, post_w, logit_w, out);
}